// Round 9
// baseline (129.124 us; speedup 1.0000x reference)
//
#include <hip/hip_runtime.h>
#include <hip/hip_bf16.h>

// ROUND 9: A/B diagnostic — identical pipeline launched TWICE per call.
// dur(single)=68.2µs is known; dur(double)=F+2K decomposes fixed replay
// overhead F vs kernel-sum K. No kernel-code changes vs round 8.

#define NN 20000
#define EE 320000
#define E4 (EE/4)
#define KK 4
#define FIN 512
#define FHID 256
#define FOUT 128
#define FHD 256
#define NH (2*FOUT+3)   // 259
#define CAP1 1024       // max L1 edges (edges into the 2 targets); expected ~32
#define MS2 128         // max unique slot nodes; expected ~35
#define BCAP 256        // max in-edges per slot node; expected ~45 worst-case

__device__ __forceinline__ float dinvf(int indeg) {
  // reference deg includes the self-loop -> always >= 1
  return rsqrtf((float)(indeg + 1));
}

// KZ: zero the counter/flag region (642 KB).
__global__ __launch_bounds__(256) void kz_zero(int4* __restrict__ p, int n4) {
  int i = blockIdx.x * 256 + threadIdx.x;
  if (i < n4) p[i] = make_int4(0, 0, 0, 0);
}

// K12: scan dst planes; collect L1 edges AND inline CAS-claim slot nodes.
__global__ __launch_bounds__(256) void k12_scan_claim(const int* __restrict__ ei,
                                                      const int* __restrict__ idx,
                                                      int* __restrict__ cnt1,
                                                      int* __restrict__ L1src,
                                                      int* __restrict__ L1sel,
                                                      int* __restrict__ reg,
                                                      int* __restrict__ slotNode,
                                                      int* __restrict__ mslots) {
  int k = blockIdx.y;
  int* rk = reg + (size_t)k * NN;
  int t0 = idx[2 * k], t1 = idx[2 * k + 1];
  if (blockIdx.x == 0 && threadIdx.x < 2) {
    int node = (threadIdx.x == 0) ? t0 : t1;
    if (atomicCAS(&rk[node], 0, -2) == 0) {
      int s = atomicAdd(&mslots[k], 1);
      if (s < MS2) { slotNode[k * MS2 + s] = node; rk[node] = s + 1; }
    }
  }
  int e4 = blockIdx.x * blockDim.x + threadIdx.x;
  if (e4 >= E4) return;
  const int* srcp = ei + (size_t)k * 2 * EE;
  int4 d4 = ((const int4*)(srcp + EE))[e4];
  int ds[4] = {d4.x, d4.y, d4.z, d4.w};
  #pragma unroll
  for (int c = 0; c < 4; c++) {
    bool h0 = (ds[c] == t0), h1 = (ds[c] == t1);
    if (h0 || h1) {
      int u = srcp[e4 * 4 + c];
      if (h0) {
        int p = atomicAdd(&cnt1[k], 1);
        if (p < CAP1) { L1src[k * CAP1 + p] = u; L1sel[k * CAP1 + p] = 0; }
      }
      if (h1) {
        int p = atomicAdd(&cnt1[k], 1);
        if (p < CAP1) { L1src[k * CAP1 + p] = u; L1sel[k * CAP1 + p] = 1; }
      }
      if (atomicCAS(&rk[u], 0, -2) == 0) {
        int s = atomicAdd(&mslots[k], 1);
        if (s < MS2) { slotNode[k * MS2 + s] = u; rk[u] = s + 1; }
      }
    }
  }
}

// K3: scan; if dst is a slot node, append src to that slot's bucket; flag src
__global__ __launch_bounds__(256) void k3_scanL2(const int* __restrict__ ei,
                                                 int* __restrict__ reg,
                                                 int* __restrict__ bcnt,
                                                 int* __restrict__ bucket) {
  int k = blockIdx.y;
  int e4 = blockIdx.x * blockDim.x + threadIdx.x;
  if (e4 >= E4) return;
  const int* srcp = ei + (size_t)k * 2 * EE;
  int4 d4 = ((const int4*)(srcp + EE))[e4];
  int* rk = reg + (size_t)k * NN;
  int ds[4] = {d4.x, d4.y, d4.z, d4.w};
  #pragma unroll
  for (int c = 0; c < 4; c++) {
    int rv = rk[ds[c]];
    if (rv > 0) {
      int s = rv - 1;
      int u = srcp[e4 * 4 + c];
      int p = atomicAdd(&bcnt[k * MS2 + s], 1);
      if (p < BCAP) bucket[((size_t)k * MS2 + s) * BCAP + p] = u;
      if (rk[u] == 0) rk[u] = -1;  // benign race: both writers store -1
    }
  }
}

// K4: scan; count in-degree only for flagged/registered nodes
__global__ __launch_bounds__(256) void k4_deg(const int* __restrict__ ei,
                                              const int* __restrict__ reg,
                                              int* __restrict__ deg) {
  int k = blockIdx.y;
  int e4 = blockIdx.x * blockDim.x + threadIdx.x;
  if (e4 >= E4) return;
  const int* dstp = ei + (size_t)k * 2 * EE + EE;
  int4 d4 = ((const int4*)dstp)[e4];
  const int* rk = reg + (size_t)k * NN;
  int ds[4] = {d4.x, d4.y, d4.z, d4.w};
  #pragma unroll
  for (int c = 0; c < 4; c++) {
    if (rk[ds[c]] != 0) atomicAdd(&deg[k * NN + ds[c]], 1);
  }
}

// K5: per slot (1024 thr): agg = dn*(dn*x[s] + sum du*x[u]); GEMV1+relu+GEMV2
__global__ __launch_bounds__(1024) void k5_slotmlp(const int* __restrict__ slotNode,
                                                   const int* __restrict__ mslots,
                                                   const int* __restrict__ bcnt,
                                                   const int* __restrict__ bucket,
                                                   const int* __restrict__ deg,
                                                   const float* __restrict__ x,
                                                   const float* __restrict__ W1,
                                                   const float* __restrict__ b1,
                                                   const float* __restrict__ W2,
                                                   float* __restrict__ HW2) {
  __shared__ float aggS[FIN];
  __shared__ float gtmp[FIN];
  __shared__ float part[4][FHID];
  __shared__ float hrow[FHID];
  __shared__ float part2[8][FOUT];
  __shared__ int   uS[BCAP];
  __shared__ float duS[BCAP];
  int k = blockIdx.y, s = blockIdx.x;
  if (s >= mslots[k]) return;
  int tid = threadIdx.x;
  int node = slotNode[k * MS2 + s];
  int nb = min(bcnt[k * MS2 + s], BCAP);
  const int* bk = bucket + ((size_t)k * MS2 + s) * BCAP;
  for (int e = tid; e < nb; e += 1024) {
    int u = bk[e];
    uS[e] = u;
    duS[e] = dinvf(deg[k * NN + u]);
  }
  __syncthreads();
  float dn = dinvf(deg[k * NN + node]);
  int f = tid & (FIN - 1), half = tid >> 9;
  float a = (half == 0) ? dn * x[(size_t)node * FIN + f] : 0.f;
  for (int e = half; e < nb; e += 2) a += duS[e] * x[(size_t)uS[e] * FIN + f];
  if (half == 1) gtmp[f] = a;
  __syncthreads();
  if (half == 0) aggS[f] = dn * (a + gtmp[f]);
  __syncthreads();
  {
    int q = tid >> 8, j = tid & (FHID - 1);
    float acc = 0.f;
    const float* w1p = W1 + (size_t)(q * 128) * FHID + j;
    const float* ap = aggS + q * 128;
    #pragma unroll 8
    for (int kk = 0; kk < 128; kk++) acc += ap[kk] * w1p[(size_t)kk * FHID];
    part[q][j] = acc;
  }
  __syncthreads();
  if (tid < FHID) {
    float v = part[0][tid] + part[1][tid] + part[2][tid] + part[3][tid] + b1[tid];
    hrow[tid] = v > 0.f ? v : 0.f;
  }
  __syncthreads();
  {
    int p = tid >> 7, j = tid & (FOUT - 1);
    float a2 = 0.f;
    const float* w2p = W2 + (size_t)(p * 32) * FOUT + j;
    const float* hp = hrow + p * 32;
    #pragma unroll 8
    for (int kk = 0; kk < 32; kk++) a2 += hp[kk] * w2p[(size_t)kk * FOUT];
    part2[p][j] = a2;
  }
  __syncthreads();
  if (tid < FOUT) {
    float sv = part2[0][tid] + part2[1][tid] + part2[2][tid] + part2[3][tid] +
               part2[4][tid] + part2[5][tid] + part2[6][tid] + part2[7][tid];
    HW2[((size_t)k * MS2 + s) * FOUT + tid] = sv;
  }
}

// K6: mu rows + decoder MLP -> sigmoid -> out[k]
__global__ __launch_bounds__(256) void k6_decode(const float* __restrict__ HW2,
                                                 const float* __restrict__ b2,
                                                 const int* __restrict__ cnt1,
                                                 const int* __restrict__ L1src,
                                                 const int* __restrict__ L1sel,
                                                 const int* __restrict__ idx,
                                                 const int* __restrict__ reg,
                                                 const int* __restrict__ deg,
                                                 const float* __restrict__ value,
                                                 const float* __restrict__ Wd,
                                                 const float* __restrict__ bd,
                                                 const float* __restrict__ Wp,
                                                 const float* __restrict__ bp,
                                                 float* __restrict__ out) {
  __shared__ float h[NH + 1];
  __shared__ float o[FHD];
  __shared__ float red[4];
  int k = blockIdx.x;
  int tid = threadIdx.x;
  const int* rk = reg + (size_t)k * NN;
  int n1 = min(cnt1[k], CAP1);
  int tsel = tid >> 7, j = tid & 127;
  int t = idx[2 * k + tsel];
  float dit = dinvf(deg[k * NN + t]);
  int tslot = rk[t] - 1;
  float acc = b2[j] + dit * dit * HW2[((size_t)k * MS2 + tslot) * FOUT + j];
  for (int i = 0; i < n1; i++) {
    if (L1sel[k * CAP1 + i] == tsel) {
      int s = L1src[k * CAP1 + i];
      float dis = dinvf(deg[k * NN + s]);
      int sslot = rk[s] - 1;
      acc += dis * dit * HW2[((size_t)k * MS2 + sslot) * FOUT + j];
    }
  }
  h[tsel * FOUT + j] = acc;
  if (tid < 3) h[2 * FOUT + tid] = value[k * 3 + tid];
  __syncthreads();
  float a2 = bd[tid];
  for (int i = 0; i < NH; i++) a2 += h[i] * Wd[(size_t)i * FHD + tid];
  o[tid] = a2 > 0.f ? a2 : 0.f;
  __syncthreads();
  float r = o[tid] * Wp[tid];
  for (int off2 = 32; off2 > 0; off2 >>= 1) r += __shfl_down(r, off2);
  if ((tid & 63) == 0) red[tid >> 6] = r;
  __syncthreads();
  if (tid == 0) {
    float ssum = red[0] + red[1] + red[2] + red[3] + bp[0];
    out[k] = 1.f / (1.f + expf(-ssum));
  }
}

extern "C" void kernel_launch(void* const* d_in, const int* in_sizes, int n_in,
                              void* d_out, int out_size, void* d_ws, size_t ws_size,
                              hipStream_t stream) {
  const float* x     = (const float*)d_in[0];
  const int*   ei    = (const int*)d_in[1];
  const float* value = (const float*)d_in[2];
  const int*   idx   = (const int*)d_in[3];
  const float* W1    = (const float*)d_in[4];
  const float* b1    = (const float*)d_in[5];
  const float* W2    = (const float*)d_in[6];
  const float* b2    = (const float*)d_in[7];
  const float* Wd    = (const float*)d_in[8];
  const float* bd    = (const float*)d_in[9];
  const float* Wp    = (const float*)d_in[10];
  const float* bp    = (const float*)d_in[11];
  float* out = (float*)d_out;

  char* ws = (char*)d_ws;
  size_t off = 0;
  auto alloc = [&](size_t bytes) -> void* {
    void* p = ws + off;
    off = (off + bytes + 255) & ~(size_t)255;
    return p;
  };
  int* reg   = (int*)alloc((size_t)(2 * KK * NN + KK * MS2 + 2 * KK) * sizeof(int));
  int* deg   = reg + KK * NN;
  int* bcnt  = deg + KK * NN;
  int* cnt1  = bcnt + KK * MS2;
  int* mslots = cnt1 + KK;
  size_t zbytes = (size_t)(2 * KK * NN + KK * MS2 + 2 * KK) * sizeof(int);  // /16 exact
  int* L1src = (int*)alloc((size_t)KK * CAP1 * sizeof(int));
  int* L1sel = (int*)alloc((size_t)KK * CAP1 * sizeof(int));
  int* slotNode = (int*)alloc((size_t)KK * MS2 * sizeof(int));
  int* bucket = (int*)alloc((size_t)KK * MS2 * BCAP * sizeof(int));
  float* HW2 = (float*)alloc((size_t)KK * MS2 * FOUT * sizeof(float));
  (void)ws_size; (void)in_sizes; (void)n_in; (void)out_size;

  int n4 = (int)(zbytes / 16);
  dim3 escan((E4 + 255) / 256, KK);

  // Pass 1 and Pass 2 are byte-identical recomputations (kz re-zeros all
  // counters), so output is deterministic. Pass 2 exists purely to measure
  // kernel-sum K vs fixed replay overhead F: dur = F + 2K.
  #pragma unroll
  for (int rep = 0; rep < 2; rep++) {
    kz_zero<<<(n4 + 255) / 256, 256, 0, stream>>>((int4*)reg, n4);
    k12_scan_claim<<<escan, 256, 0, stream>>>(ei, idx, cnt1, L1src, L1sel,
                                              reg, slotNode, mslots);
    k3_scanL2<<<escan, 256, 0, stream>>>(ei, reg, bcnt, bucket);
    k4_deg<<<escan, 256, 0, stream>>>(ei, reg, deg);
    k5_slotmlp<<<dim3(MS2, KK), 1024, 0, stream>>>(slotNode, mslots, bcnt, bucket, deg,
                                                   x, W1, b1, W2, HW2);
    k6_decode<<<dim3(KK), 256, 0, stream>>>(HW2, b2, cnt1, L1src, L1sel, idx, reg, deg,
                                            value, Wd, bd, Wp, bp, out);
  }
}

// Round 11
// 110.626 us; speedup vs baseline: 1.1672x; 1.1672x over previous
//
#include <hip/hip_runtime.h>
#include <hip/hip_bf16.h>

// ROUND 11 diagnostic: round-8 pipeline + 3 extra IDEMPOTENT k5 launches.
// k5 is pure (no atomics): reruns rewrite HW2 with identical bytes.
// dur = base(68.2) + 3*k5  ->  isolates k5's true cost.

#define NN 20000
#define EE 320000
#define E4 (EE/4)
#define KK 4
#define FIN 512
#define FHID 256
#define FOUT 128
#define FHD 256
#define NH (2*FOUT+3)   // 259
#define CAP1 1024
#define MS2 128
#define BCAP 256

__device__ __forceinline__ float dinvf(int indeg) {
  return rsqrtf((float)(indeg + 1));
}

__global__ __launch_bounds__(256) void kz_zero(int4* __restrict__ p, int n4) {
  int i = blockIdx.x * 256 + threadIdx.x;
  if (i < n4) p[i] = make_int4(0, 0, 0, 0);
}

// K12: scan dst planes; collect L1 edges AND inline CAS-claim slot nodes.
__global__ __launch_bounds__(256) void k12_scan_claim(const int* __restrict__ ei,
                                                      const int* __restrict__ idx,
                                                      int* __restrict__ cnt1,
                                                      int* __restrict__ L1src,
                                                      int* __restrict__ L1sel,
                                                      int* __restrict__ reg,
                                                      int* __restrict__ slotNode,
                                                      int* __restrict__ mslots) {
  int k = blockIdx.y;
  int* rk = reg + (size_t)k * NN;
  int t0 = idx[2 * k], t1 = idx[2 * k + 1];
  if (blockIdx.x == 0 && threadIdx.x < 2) {
    int node = (threadIdx.x == 0) ? t0 : t1;
    if (atomicCAS(&rk[node], 0, -2) == 0) {
      int s = atomicAdd(&mslots[k], 1);
      if (s < MS2) { slotNode[k * MS2 + s] = node; rk[node] = s + 1; }
    }
  }
  int e4 = blockIdx.x * blockDim.x + threadIdx.x;
  if (e4 >= E4) return;
  const int* srcp = ei + (size_t)k * 2 * EE;
  int4 d4 = ((const int4*)(srcp + EE))[e4];
  int ds[4] = {d4.x, d4.y, d4.z, d4.w};
  #pragma unroll
  for (int c = 0; c < 4; c++) {
    bool h0 = (ds[c] == t0), h1 = (ds[c] == t1);
    if (h0 || h1) {
      int u = srcp[e4 * 4 + c];
      if (h0) {
        int p = atomicAdd(&cnt1[k], 1);
        if (p < CAP1) { L1src[k * CAP1 + p] = u; L1sel[k * CAP1 + p] = 0; }
      }
      if (h1) {
        int p = atomicAdd(&cnt1[k], 1);
        if (p < CAP1) { L1src[k * CAP1 + p] = u; L1sel[k * CAP1 + p] = 1; }
      }
      if (atomicCAS(&rk[u], 0, -2) == 0) {
        int s = atomicAdd(&mslots[k], 1);
        if (s < MS2) { slotNode[k * MS2 + s] = u; rk[u] = s + 1; }
      }
    }
  }
}

// K3: scan; if dst is a slot node, append src to that slot's bucket; flag src
__global__ __launch_bounds__(256) void k3_scanL2(const int* __restrict__ ei,
                                                 int* __restrict__ reg,
                                                 int* __restrict__ bcnt,
                                                 int* __restrict__ bucket) {
  int k = blockIdx.y;
  int e4 = blockIdx.x * blockDim.x + threadIdx.x;
  if (e4 >= E4) return;
  const int* srcp = ei + (size_t)k * 2 * EE;
  int4 d4 = ((const int4*)(srcp + EE))[e4];
  int* rk = reg + (size_t)k * NN;
  int ds[4] = {d4.x, d4.y, d4.z, d4.w};
  #pragma unroll
  for (int c = 0; c < 4; c++) {
    int rv = rk[ds[c]];
    if (rv > 0) {
      int s = rv - 1;
      int u = srcp[e4 * 4 + c];
      int p = atomicAdd(&bcnt[k * MS2 + s], 1);
      if (p < BCAP) bucket[((size_t)k * MS2 + s) * BCAP + p] = u;
      if (rk[u] == 0) rk[u] = -1;  // benign race
    }
  }
}

// K4: scan; count in-degree only for flagged/registered nodes
__global__ __launch_bounds__(256) void k4_deg(const int* __restrict__ ei,
                                              const int* __restrict__ reg,
                                              int* __restrict__ deg) {
  int k = blockIdx.y;
  int e4 = blockIdx.x * blockDim.x + threadIdx.x;
  if (e4 >= E4) return;
  const int* dstp = ei + (size_t)k * 2 * EE + EE;
  int4 d4 = ((const int4*)dstp)[e4];
  const int* rk = reg + (size_t)k * NN;
  int ds[4] = {d4.x, d4.y, d4.z, d4.w};
  #pragma unroll
  for (int c = 0; c < 4; c++) {
    if (rk[ds[c]] != 0) atomicAdd(&deg[k * NN + ds[c]], 1);
  }
}

// K5: per slot (1024 thr): agg = dn*(dn*x[s] + sum du*x[u]); GEMV1+relu+GEMV2
__global__ __launch_bounds__(1024) void k5_slotmlp(const int* __restrict__ slotNode,
                                                   const int* __restrict__ mslots,
                                                   const int* __restrict__ bcnt,
                                                   const int* __restrict__ bucket,
                                                   const int* __restrict__ deg,
                                                   const float* __restrict__ x,
                                                   const float* __restrict__ W1,
                                                   const float* __restrict__ b1,
                                                   const float* __restrict__ W2,
                                                   float* __restrict__ HW2) {
  __shared__ float aggS[FIN];
  __shared__ float gtmp[FIN];
  __shared__ float part[4][FHID];
  __shared__ float hrow[FHID];
  __shared__ float part2[8][FOUT];
  __shared__ int   uS[BCAP];
  __shared__ float duS[BCAP];
  int k = blockIdx.y, s = blockIdx.x;
  if (s >= mslots[k]) return;
  int tid = threadIdx.x;
  int node = slotNode[k * MS2 + s];
  int nb = min(bcnt[k * MS2 + s], BCAP);
  const int* bk = bucket + ((size_t)k * MS2 + s) * BCAP;
  for (int e = tid; e < nb; e += 1024) {
    int u = bk[e];
    uS[e] = u;
    duS[e] = dinvf(deg[k * NN + u]);
  }
  __syncthreads();
  float dn = dinvf(deg[k * NN + node]);
  int f = tid & (FIN - 1), half = tid >> 9;
  float a = (half == 0) ? dn * x[(size_t)node * FIN + f] : 0.f;
  for (int e = half; e < nb; e += 2) a += duS[e] * x[(size_t)uS[e] * FIN + f];
  if (half == 1) gtmp[f] = a;
  __syncthreads();
  if (half == 0) aggS[f] = dn * (a + gtmp[f]);
  __syncthreads();
  {
    int q = tid >> 8, j = tid & (FHID - 1);
    float acc = 0.f;
    const float* w1p = W1 + (size_t)(q * 128) * FHID + j;
    const float* ap = aggS + q * 128;
    #pragma unroll 8
    for (int kk = 0; kk < 128; kk++) acc += ap[kk] * w1p[(size_t)kk * FHID];
    part[q][j] = acc;
  }
  __syncthreads();
  if (tid < FHID) {
    float v = part[0][tid] + part[1][tid] + part[2][tid] + part[3][tid] + b1[tid];
    hrow[tid] = v > 0.f ? v : 0.f;
  }
  __syncthreads();
  {
    int p = tid >> 7, j = tid & (FOUT - 1);
    float a2 = 0.f;
    const float* w2p = W2 + (size_t)(p * 32) * FOUT + j;
    const float* hp = hrow + p * 32;
    #pragma unroll 8
    for (int kk = 0; kk < 32; kk++) a2 += hp[kk] * w2p[(size_t)kk * FOUT];
    part2[p][j] = a2;
  }
  __syncthreads();
  if (tid < FOUT) {
    float sv = part2[0][tid] + part2[1][tid] + part2[2][tid] + part2[3][tid] +
               part2[4][tid] + part2[5][tid] + part2[6][tid] + part2[7][tid];
    HW2[((size_t)k * MS2 + s) * FOUT + tid] = sv;
  }
}

// K6: mu rows + decoder MLP -> sigmoid -> out[k]
__global__ __launch_bounds__(256) void k6_decode(const float* __restrict__ HW2,
                                                 const float* __restrict__ b2,
                                                 const int* __restrict__ cnt1,
                                                 const int* __restrict__ L1src,
                                                 const int* __restrict__ L1sel,
                                                 const int* __restrict__ idx,
                                                 const int* __restrict__ reg,
                                                 const int* __restrict__ deg,
                                                 const float* __restrict__ value,
                                                 const float* __restrict__ Wd,
                                                 const float* __restrict__ bd,
                                                 const float* __restrict__ Wp,
                                                 const float* __restrict__ bp,
                                                 float* __restrict__ out) {
  __shared__ float h[NH + 1];
  __shared__ float o[FHD];
  __shared__ float red[4];
  int k = blockIdx.x;
  int tid = threadIdx.x;
  const int* rk = reg + (size_t)k * NN;
  int n1 = min(cnt1[k], CAP1);
  int tsel = tid >> 7, j = tid & 127;
  int t = idx[2 * k + tsel];
  float dit = dinvf(deg[k * NN + t]);
  int tslot = rk[t] - 1;
  float acc = b2[j] + dit * dit * HW2[((size_t)k * MS2 + tslot) * FOUT + j];
  for (int i = 0; i < n1; i++) {
    if (L1sel[k * CAP1 + i] == tsel) {
      int s = L1src[k * CAP1 + i];
      float dis = dinvf(deg[k * NN + s]);
      int sslot = rk[s] - 1;
      acc += dis * dit * HW2[((size_t)k * MS2 + sslot) * FOUT + j];
    }
  }
  h[tsel * FOUT + j] = acc;
  if (tid < 3) h[2 * FOUT + tid] = value[k * 3 + tid];
  __syncthreads();
  float a2 = bd[tid];
  for (int i = 0; i < NH; i++) a2 += h[i] * Wd[(size_t)i * FHD + tid];
  o[tid] = a2 > 0.f ? a2 : 0.f;
  __syncthreads();
  float r = o[tid] * Wp[tid];
  for (int off2 = 32; off2 > 0; off2 >>= 1) r += __shfl_down(r, off2);
  if ((tid & 63) == 0) red[tid >> 6] = r;
  __syncthreads();
  if (tid == 0) {
    float ssum = red[0] + red[1] + red[2] + red[3] + bp[0];
    out[k] = 1.f / (1.f + expf(-ssum));
  }
}

extern "C" void kernel_launch(void* const* d_in, const int* in_sizes, int n_in,
                              void* d_out, int out_size, void* d_ws, size_t ws_size,
                              hipStream_t stream) {
  const float* x     = (const float*)d_in[0];
  const int*   ei    = (const int*)d_in[1];
  const float* value = (const float*)d_in[2];
  const int*   idx   = (const int*)d_in[3];
  const float* W1    = (const float*)d_in[4];
  const float* b1    = (const float*)d_in[5];
  const float* W2    = (const float*)d_in[6];
  const float* b2    = (const float*)d_in[7];
  const float* Wd    = (const float*)d_in[8];
  const float* bd    = (const float*)d_in[9];
  const float* Wp    = (const float*)d_in[10];
  const float* bp    = (const float*)d_in[11];
  float* out = (float*)d_out;

  char* ws = (char*)d_ws;
  size_t off = 0;
  auto alloc = [&](size_t bytes) -> void* {
    void* p = ws + off;
    off = (off + bytes + 255) & ~(size_t)255;
    return p;
  };
  int* reg   = (int*)alloc((size_t)(2 * KK * NN + KK * MS2 + 2 * KK) * sizeof(int));
  int* deg   = reg + KK * NN;
  int* bcnt  = deg + KK * NN;
  int* cnt1  = bcnt + KK * MS2;
  int* mslots = cnt1 + KK;
  size_t zbytes = (size_t)(2 * KK * NN + KK * MS2 + 2 * KK) * sizeof(int);  // /16 exact
  int* L1src = (int*)alloc((size_t)KK * CAP1 * sizeof(int));
  int* L1sel = (int*)alloc((size_t)KK * CAP1 * sizeof(int));
  int* slotNode = (int*)alloc((size_t)KK * MS2 * sizeof(int));
  int* bucket = (int*)alloc((size_t)KK * MS2 * BCAP * sizeof(int));
  float* HW2 = (float*)alloc((size_t)KK * MS2 * FOUT * sizeof(float));
  (void)ws_size; (void)in_sizes; (void)n_in; (void)out_size;

  int n4 = (int)(zbytes / 16);
  dim3 escan((E4 + 255) / 256, KK);

  kz_zero<<<(n4 + 255) / 256, 256, 0, stream>>>((int4*)reg, n4);
  k12_scan_claim<<<escan, 256, 0, stream>>>(ei, idx, cnt1, L1src, L1sel,
                                            reg, slotNode, mslots);
  k3_scanL2<<<escan, 256, 0, stream>>>(ei, reg, bcnt, bucket);
  k4_deg<<<escan, 256, 0, stream>>>(ei, reg, deg);
  k5_slotmlp<<<dim3(MS2, KK), 1024, 0, stream>>>(slotNode, mslots, bcnt, bucket, deg,
                                                 x, W1, b1, W2, HW2);
  // --- diagnostic amplification: k5 is idempotent (pure, no atomics) ---
  k5_slotmlp<<<dim3(MS2, KK), 1024, 0, stream>>>(slotNode, mslots, bcnt, bucket, deg,
                                                 x, W1, b1, W2, HW2);
  k5_slotmlp<<<dim3(MS2, KK), 1024, 0, stream>>>(slotNode, mslots, bcnt, bucket, deg,
                                                 x, W1, b1, W2, HW2);
  k5_slotmlp<<<dim3(MS2, KK), 1024, 0, stream>>>(slotNode, mslots, bcnt, bucket, deg,
                                                 x, W1, b1, W2, HW2);
  k6_decode<<<dim3(KK), 256, 0, stream>>>(HW2, b2, cnt1, L1src, L1sel, idx, reg, deg,
                                          value, Wd, bd, Wp, bp, out);
}

// Round 12
// 109.046 us; speedup vs baseline: 1.1841x; 1.0145x over previous
//
#include <hip/hip_runtime.h>
#include <hip/hip_bf16.h>

#define NN 20000
#define EE 320000
#define E4 (EE/4)
#define KK 4
#define FIN 512
#define FHID 256
#define FOUT 128
#define FHD 256
#define NH (2*FOUT+3)   // 259
#define CAP1 1024
#define MS2 128
#define BCAP 256
#define SCANB 160       // blocks per k-plane for edge scans (grid-stride)

__device__ __forceinline__ float dinvf(int indeg) {
  // reference deg includes the self-loop -> always >= 1
  return rsqrtf((float)(indeg + 1));
}

__global__ __launch_bounds__(256) void kz_zero(int4* __restrict__ p, int n4) {
  int i = blockIdx.x * 256 + threadIdx.x;
  if (i < n4) p[i] = make_int4(0, 0, 0, 0);
}

// K12D: ONE dst-plane scan doing three jobs:
//  (1) unconditional in-degree histogram (replaces old k4 — full histogram
//      gives identical deg values for every node later used, order-independent)
//  (2) L1 edge collection (dst == t0/t1)
//  (3) CAS-claim slot registration for targets + L1 sources
__global__ __launch_bounds__(256) void k12d_scan(const int* __restrict__ ei,
                                                 const int* __restrict__ idx,
                                                 int* __restrict__ cnt1,
                                                 int* __restrict__ L1src,
                                                 int* __restrict__ L1sel,
                                                 int* __restrict__ reg,
                                                 int* __restrict__ slotNode,
                                                 int* __restrict__ mslots,
                                                 int* __restrict__ deg) {
  int k = blockIdx.y;
  int* rk = reg + (size_t)k * NN;
  int* dk = deg + k * NN;
  int t0 = idx[2 * k], t1 = idx[2 * k + 1];
  if (blockIdx.x == 0 && threadIdx.x < 2) {
    int node = (threadIdx.x == 0) ? t0 : t1;
    if (atomicCAS(&rk[node], 0, -2) == 0) {
      int s = atomicAdd(&mslots[k], 1);
      if (s < MS2) { slotNode[k * MS2 + s] = node; rk[node] = s + 1; }
    }
  }
  const int* srcp = ei + (size_t)k * 2 * EE;
  const int4* dst4 = (const int4*)(srcp + EE);
  for (int e4 = blockIdx.x * 256 + threadIdx.x; e4 < E4; e4 += SCANB * 256) {
    int4 d4 = dst4[e4];
    int ds[4] = {d4.x, d4.y, d4.z, d4.w};
    #pragma unroll
    for (int c = 0; c < 4; c++) {
      atomicAdd(dk + ds[c], 1);  // degree histogram
      bool h0 = (ds[c] == t0), h1 = (ds[c] == t1);
      if (h0 || h1) {
        int u = srcp[e4 * 4 + c];
        if (h0) {
          int p = atomicAdd(&cnt1[k], 1);
          if (p < CAP1) { L1src[k * CAP1 + p] = u; L1sel[k * CAP1 + p] = 0; }
        }
        if (h1) {
          int p = atomicAdd(&cnt1[k], 1);
          if (p < CAP1) { L1src[k * CAP1 + p] = u; L1sel[k * CAP1 + p] = 1; }
        }
        if (atomicCAS(&rk[u], 0, -2) == 0) {
          int s = atomicAdd(&mslots[k], 1);
          if (s < MS2) { slotNode[k * MS2 + s] = u; rk[u] = s + 1; }
        }
      }
    }
  }
}

// K3: scan; if dst is a slot node, append src to that slot's bucket.
// (no flag stores anymore — degrees already complete from k12d)
__global__ __launch_bounds__(256) void k3_scanL2(const int* __restrict__ ei,
                                                 const int* __restrict__ reg,
                                                 int* __restrict__ bcnt,
                                                 int* __restrict__ bucket) {
  int k = blockIdx.y;
  const int* srcp = ei + (size_t)k * 2 * EE;
  const int4* dst4 = (const int4*)(srcp + EE);
  const int* rk = reg + (size_t)k * NN;
  for (int e4 = blockIdx.x * 256 + threadIdx.x; e4 < E4; e4 += SCANB * 256) {
    int4 d4 = dst4[e4];
    int ds[4] = {d4.x, d4.y, d4.z, d4.w};
    #pragma unroll
    for (int c = 0; c < 4; c++) {
      int rv = rk[ds[c]];
      if (rv > 0) {
        int s = rv - 1;
        int u = srcp[e4 * 4 + c];
        int p = atomicAdd(&bcnt[k * MS2 + s], 1);
        if (p < BCAP) bucket[((size_t)k * MS2 + s) * BCAP + p] = u;
      }
    }
  }
}

// K5: per slot (1024 thr): agg = dn*(dn*x[s] + sum du*x[u]); GEMV1+relu+GEMV2.
// Gather unrolled x4 (independent accumulators) to cut the serial HBM-latency chain.
__global__ __launch_bounds__(1024) void k5_slotmlp(const int* __restrict__ slotNode,
                                                   const int* __restrict__ mslots,
                                                   const int* __restrict__ bcnt,
                                                   const int* __restrict__ bucket,
                                                   const int* __restrict__ deg,
                                                   const float* __restrict__ x,
                                                   const float* __restrict__ W1,
                                                   const float* __restrict__ b1,
                                                   const float* __restrict__ W2,
                                                   float* __restrict__ HW2) {
  __shared__ float aggS[FIN];
  __shared__ float gtmp[FIN];
  __shared__ float part[4][FHID];
  __shared__ float hrow[FHID];
  __shared__ float part2[8][FOUT];
  __shared__ int   uS[BCAP];
  __shared__ float duS[BCAP];
  int k = blockIdx.y, s = blockIdx.x;
  if (s >= mslots[k]) return;
  int tid = threadIdx.x;
  int node = slotNode[k * MS2 + s];
  int nb = min(bcnt[k * MS2 + s], BCAP);
  const int* bk = bucket + ((size_t)k * MS2 + s) * BCAP;
  for (int e = tid; e < nb; e += 1024) {
    int u = bk[e];
    uS[e] = u;
    duS[e] = dinvf(deg[k * NN + u]);
  }
  __syncthreads();
  float dn = dinvf(deg[k * NN + node]);
  int f = tid & (FIN - 1), half = tid >> 9;
  float a0 = (half == 0) ? dn * x[(size_t)node * FIN + f] : 0.f;
  float a1 = 0.f, a2g = 0.f, a3 = 0.f;
  int e = half;
  for (; e + 6 < nb; e += 8) {   // 4 independent loads in flight per half
    a0  += duS[e]     * x[(size_t)uS[e]     * FIN + f];
    a1  += duS[e + 2] * x[(size_t)uS[e + 2] * FIN + f];
    a2g += duS[e + 4] * x[(size_t)uS[e + 4] * FIN + f];
    a3  += duS[e + 6] * x[(size_t)uS[e + 6] * FIN + f];
  }
  for (; e < nb; e += 2) a0 += duS[e] * x[(size_t)uS[e] * FIN + f];
  float a = (a0 + a1) + (a2g + a3);
  if (half == 1) gtmp[f] = a;
  __syncthreads();
  if (half == 0) aggS[f] = dn * (a + gtmp[f]);
  __syncthreads();
  {
    int q = tid >> 8, j = tid & (FHID - 1);
    float acc = 0.f;
    const float* w1p = W1 + (size_t)(q * 128) * FHID + j;
    const float* ap = aggS + q * 128;
    #pragma unroll 8
    for (int kk = 0; kk < 128; kk++) acc += ap[kk] * w1p[(size_t)kk * FHID];
    part[q][j] = acc;
  }
  __syncthreads();
  if (tid < FHID) {
    float v = part[0][tid] + part[1][tid] + part[2][tid] + part[3][tid] + b1[tid];
    hrow[tid] = v > 0.f ? v : 0.f;
  }
  __syncthreads();
  {
    int p = tid >> 7, j = tid & (FOUT - 1);
    float a2 = 0.f;
    const float* w2p = W2 + (size_t)(p * 32) * FOUT + j;
    const float* hp = hrow + p * 32;
    #pragma unroll 8
    for (int kk = 0; kk < 32; kk++) a2 += hp[kk] * w2p[(size_t)kk * FOUT];
    part2[p][j] = a2;
  }
  __syncthreads();
  if (tid < FOUT) {
    float sv = part2[0][tid] + part2[1][tid] + part2[2][tid] + part2[3][tid] +
               part2[4][tid] + part2[5][tid] + part2[6][tid] + part2[7][tid];
    HW2[((size_t)k * MS2 + s) * FOUT + tid] = sv;
  }
}

// K6: mu rows + decoder MLP -> sigmoid -> out[k]
__global__ __launch_bounds__(256) void k6_decode(const float* __restrict__ HW2,
                                                 const float* __restrict__ b2,
                                                 const int* __restrict__ cnt1,
                                                 const int* __restrict__ L1src,
                                                 const int* __restrict__ L1sel,
                                                 const int* __restrict__ idx,
                                                 const int* __restrict__ reg,
                                                 const int* __restrict__ deg,
                                                 const float* __restrict__ value,
                                                 const float* __restrict__ Wd,
                                                 const float* __restrict__ bd,
                                                 const float* __restrict__ Wp,
                                                 const float* __restrict__ bp,
                                                 float* __restrict__ out) {
  __shared__ float h[NH + 1];
  __shared__ float o[FHD];
  __shared__ float red[4];
  int k = blockIdx.x;
  int tid = threadIdx.x;
  const int* rk = reg + (size_t)k * NN;
  int n1 = min(cnt1[k], CAP1);
  int tsel = tid >> 7, j = tid & 127;
  int t = idx[2 * k + tsel];
  float dit = dinvf(deg[k * NN + t]);
  int tslot = rk[t] - 1;
  float acc = b2[j] + dit * dit * HW2[((size_t)k * MS2 + tslot) * FOUT + j];
  for (int i = 0; i < n1; i++) {
    if (L1sel[k * CAP1 + i] == tsel) {
      int s = L1src[k * CAP1 + i];
      float dis = dinvf(deg[k * NN + s]);
      int sslot = rk[s] - 1;
      acc += dis * dit * HW2[((size_t)k * MS2 + sslot) * FOUT + j];
    }
  }
  h[tsel * FOUT + j] = acc;
  if (tid < 3) h[2 * FOUT + tid] = value[k * 3 + tid];
  __syncthreads();
  float a2 = bd[tid];
  for (int i = 0; i < NH; i++) a2 += h[i] * Wd[(size_t)i * FHD + tid];
  o[tid] = a2 > 0.f ? a2 : 0.f;
  __syncthreads();
  float r = o[tid] * Wp[tid];
  for (int off2 = 32; off2 > 0; off2 >>= 1) r += __shfl_down(r, off2);
  if ((tid & 63) == 0) red[tid >> 6] = r;
  __syncthreads();
  if (tid == 0) {
    float ssum = red[0] + red[1] + red[2] + red[3] + bp[0];
    out[k] = 1.f / (1.f + expf(-ssum));
  }
}

extern "C" void kernel_launch(void* const* d_in, const int* in_sizes, int n_in,
                              void* d_out, int out_size, void* d_ws, size_t ws_size,
                              hipStream_t stream) {
  const float* x     = (const float*)d_in[0];
  const int*   ei    = (const int*)d_in[1];
  const float* value = (const float*)d_in[2];
  const int*   idx   = (const int*)d_in[3];
  const float* W1    = (const float*)d_in[4];
  const float* b1    = (const float*)d_in[5];
  const float* W2    = (const float*)d_in[6];
  const float* b2    = (const float*)d_in[7];
  const float* Wd    = (const float*)d_in[8];
  const float* bd    = (const float*)d_in[9];
  const float* Wp    = (const float*)d_in[10];
  const float* bp    = (const float*)d_in[11];
  float* out = (float*)d_out;

  char* ws = (char*)d_ws;
  size_t off = 0;
  auto alloc = [&](size_t bytes) -> void* {
    void* p = ws + off;
    off = (off + bytes + 255) & ~(size_t)255;
    return p;
  };
  int* reg   = (int*)alloc((size_t)(2 * KK * NN + KK * MS2 + 2 * KK) * sizeof(int));
  int* deg   = reg + KK * NN;
  int* bcnt  = deg + KK * NN;
  int* cnt1  = bcnt + KK * MS2;
  int* mslots = cnt1 + KK;
  size_t zbytes = (size_t)(2 * KK * NN + KK * MS2 + 2 * KK) * sizeof(int);  // /16 exact
  int* L1src = (int*)alloc((size_t)KK * CAP1 * sizeof(int));
  int* L1sel = (int*)alloc((size_t)KK * CAP1 * sizeof(int));
  int* slotNode = (int*)alloc((size_t)KK * MS2 * sizeof(int));
  int* bucket = (int*)alloc((size_t)KK * MS2 * BCAP * sizeof(int));
  float* HW2 = (float*)alloc((size_t)KK * MS2 * FOUT * sizeof(float));
  (void)ws_size; (void)in_sizes; (void)n_in; (void)out_size;

  int n4 = (int)(zbytes / 16);
  dim3 escan(SCANB, KK);

  kz_zero<<<(n4 + 255) / 256, 256, 0, stream>>>((int4*)reg, n4);
  k12d_scan<<<escan, 256, 0, stream>>>(ei, idx, cnt1, L1src, L1sel,
                                       reg, slotNode, mslots, deg);
  k3_scanL2<<<escan, 256, 0, stream>>>(ei, reg, bcnt, bucket);
  k5_slotmlp<<<dim3(MS2, KK), 1024, 0, stream>>>(slotNode, mslots, bcnt, bucket, deg,
                                                 x, W1, b1, W2, HW2);
  k6_decode<<<dim3(KK), 256, 0, stream>>>(HW2, b2, cnt1, L1src, L1sel, idx, reg, deg,
                                          value, Wd, bd, Wp, bp, out);
}

// Round 13
// 90.779 us; speedup vs baseline: 1.4224x; 1.2012x over previous
//
#include <hip/hip_runtime.h>
#include <hip/hip_bf16.h>

#define NN 20000
#define EE 320000
#define E4 (EE/4)
#define KK 4
#define FIN 512
#define FHID 256
#define FOUT 128
#define FHD 256
#define NH (2*FOUT+3)   // 259
#define CAP1 1024
#define MS2 128
#define BCAP 256
#define CH 16           // edge chunks per plane for k3h
#define HALF 10000      // node-range half size (2*HALF == NN)
#define EPC (EE/CH)     // 20000 edges per chunk
#define I4PC (EPC/4)    // 5000 int4 per chunk

__device__ __forceinline__ float dinvf(int indeg) {
  // reference deg includes the self-loop -> always >= 1
  return rsqrtf((float)(indeg + 1));
}

__global__ __launch_bounds__(256) void kz_zero(int4* __restrict__ p, int n4) {
  int i = blockIdx.x * 256 + threadIdx.x;
  if (i < n4) p[i] = make_int4(0, 0, 0, 0);
}

// K12: scan dst planes; collect L1 edges AND inline CAS-claim slot nodes (round-8 proven).
__global__ __launch_bounds__(256) void k12_scan_claim(const int* __restrict__ ei,
                                                      const int* __restrict__ idx,
                                                      int* __restrict__ cnt1,
                                                      int* __restrict__ L1src,
                                                      int* __restrict__ L1sel,
                                                      int* __restrict__ reg,
                                                      int* __restrict__ slotNode,
                                                      int* __restrict__ mslots) {
  int k = blockIdx.y;
  int* rk = reg + (size_t)k * NN;
  int t0 = idx[2 * k], t1 = idx[2 * k + 1];
  if (blockIdx.x == 0 && threadIdx.x < 2) {
    int node = (threadIdx.x == 0) ? t0 : t1;
    if (atomicCAS(&rk[node], 0, -2) == 0) {
      int s = atomicAdd(&mslots[k], 1);
      if (s < MS2) { slotNode[k * MS2 + s] = node; rk[node] = s + 1; }
    }
  }
  int e4 = blockIdx.x * blockDim.x + threadIdx.x;
  if (e4 >= E4) return;
  const int* srcp = ei + (size_t)k * 2 * EE;
  int4 d4 = ((const int4*)(srcp + EE))[e4];
  int ds[4] = {d4.x, d4.y, d4.z, d4.w};
  #pragma unroll
  for (int c = 0; c < 4; c++) {
    bool h0 = (ds[c] == t0), h1 = (ds[c] == t1);
    if (h0 || h1) {
      int u = srcp[e4 * 4 + c];
      if (h0) {
        int p = atomicAdd(&cnt1[k], 1);
        if (p < CAP1) { L1src[k * CAP1 + p] = u; L1sel[k * CAP1 + p] = 0; }
      }
      if (h1) {
        int p = atomicAdd(&cnt1[k], 1);
        if (p < CAP1) { L1src[k * CAP1 + p] = u; L1sel[k * CAP1 + p] = 1; }
      }
      if (atomicCAS(&rk[u], 0, -2) == 0) {
        int s = atomicAdd(&mslots[k], 1);
        if (s < MS2) { slotNode[k * MS2 + s] = u; rk[u] = s + 1; }
      }
    }
  }
}

// K3H: ONE scan doing (a) bucket append (half==0 blocks, all edges exactly once)
// and (b) LDS-privatized degree histogram (block owns chunk cx × node-half).
// Partials STORED (coalesced, no atomic merge) -> P[k][cx][node]. No HBM RMWs.
__global__ __launch_bounds__(256) void k3h_scan(const int* __restrict__ ei,
                                                const int* __restrict__ reg,
                                                int* __restrict__ bcnt,
                                                int* __restrict__ bucket,
                                                unsigned* __restrict__ P) {
  __shared__ unsigned lh[HALF];   // 40 KB
  int k = blockIdx.y;
  int cx = blockIdx.x >> 1, half = blockIdx.x & 1;
  int nbase = half * HALF;
  for (int i = threadIdx.x; i < HALF; i += 256) lh[i] = 0u;
  __syncthreads();
  const int* srcp = ei + (size_t)k * 2 * EE;
  const int4* dst4 = (const int4*)(srcp + EE);
  const int* rk = reg + (size_t)k * NN;
  int i40 = cx * I4PC;
  for (int i = threadIdx.x; i < I4PC; i += 256) {
    int4 d4 = dst4[i40 + i];
    int ds[4] = {d4.x, d4.y, d4.z, d4.w};
    #pragma unroll
    for (int c = 0; c < 4; c++) {
      int d = ds[c];
      unsigned rel = (unsigned)(d - nbase);
      if (rel < (unsigned)HALF) atomicAdd(&lh[rel], 1u);
      if (half == 0) {
        int rv = rk[d];
        if (rv > 0) {
          int s = rv - 1;
          int u = srcp[(i40 + i) * 4 + c];
          int p = atomicAdd(&bcnt[k * MS2 + s], 1);
          if (p < BCAP) bucket[((size_t)k * MS2 + s) * BCAP + p] = u;
        }
      }
    }
  }
  __syncthreads();
  unsigned* Pk = P + ((size_t)k * CH + cx) * NN + nbase;
  for (int i = threadIdx.x; i < HALF; i += 256) Pk[i] = lh[i];
}

// K5: per slot (1024 thr). Slot degree = raw bcnt; bucket-source degrees = sum of
// 16 chunk-partials (16 lanes per entry). Then gather + GEMV1 + relu + GEMV2.
__global__ __launch_bounds__(1024) void k5_slotmlp(const int* __restrict__ slotNode,
                                                   const int* __restrict__ mslots,
                                                   const int* __restrict__ bcnt,
                                                   const int* __restrict__ bucket,
                                                   const unsigned* __restrict__ P,
                                                   const float* __restrict__ x,
                                                   const float* __restrict__ W1,
                                                   const float* __restrict__ b1,
                                                   const float* __restrict__ W2,
                                                   float* __restrict__ HW2) {
  __shared__ float aggS[FIN];
  __shared__ float gtmp[FIN];
  __shared__ float part[4][FHID];
  __shared__ float hrow[FHID];
  __shared__ float part2[8][FOUT];
  __shared__ int      uS[BCAP];
  __shared__ unsigned duI[BCAP];
  __shared__ float    duS[BCAP];
  int k = blockIdx.y, s = blockIdx.x;
  if (s >= mslots[k]) return;
  int tid = threadIdx.x;
  int node = slotNode[k * MS2 + s];
  int rawbc = bcnt[k * MS2 + s];
  int nb = min(rawbc, BCAP);
  const int* bk = bucket + ((size_t)k * MS2 + s) * BCAP;
  if (tid < nb) { uS[tid] = bk[tid]; duI[tid] = 0u; }
  __syncthreads();
  for (int i = tid; i < nb * CH; i += 1024) {
    int e = i >> 4, cx = i & (CH - 1);
    atomicAdd(&duI[e], P[((size_t)k * CH + cx) * NN + uS[e]]);
  }
  __syncthreads();
  if (tid < nb) duS[tid] = dinvf((int)duI[tid]);
  __syncthreads();
  float dn = dinvf(rawbc);   // slot in-degree == bucket count
  int f = tid & (FIN - 1), half = tid >> 9;
  float a0 = (half == 0) ? dn * x[(size_t)node * FIN + f] : 0.f;
  float a1 = 0.f, a2g = 0.f, a3 = 0.f;
  int e = half;
  for (; e + 6 < nb; e += 8) {
    a0  += duS[e]     * x[(size_t)uS[e]     * FIN + f];
    a1  += duS[e + 2] * x[(size_t)uS[e + 2] * FIN + f];
    a2g += duS[e + 4] * x[(size_t)uS[e + 4] * FIN + f];
    a3  += duS[e + 6] * x[(size_t)uS[e + 6] * FIN + f];
  }
  for (; e < nb; e += 2) a0 += duS[e] * x[(size_t)uS[e] * FIN + f];
  float a = (a0 + a1) + (a2g + a3);
  if (half == 1) gtmp[f] = a;
  __syncthreads();
  if (half == 0) aggS[f] = dn * (a + gtmp[f]);
  __syncthreads();
  {
    int q = tid >> 8, j = tid & (FHID - 1);
    float acc = 0.f;
    const float* w1p = W1 + (size_t)(q * 128) * FHID + j;
    const float* ap = aggS + q * 128;
    #pragma unroll 8
    for (int kk = 0; kk < 128; kk++) acc += ap[kk] * w1p[(size_t)kk * FHID];
    part[q][j] = acc;
  }
  __syncthreads();
  if (tid < FHID) {
    float v = part[0][tid] + part[1][tid] + part[2][tid] + part[3][tid] + b1[tid];
    hrow[tid] = v > 0.f ? v : 0.f;
  }
  __syncthreads();
  {
    int p = tid >> 7, j = tid & (FOUT - 1);
    float a2 = 0.f;
    const float* w2p = W2 + (size_t)(p * 32) * FOUT + j;
    const float* hp = hrow + p * 32;
    #pragma unroll 8
    for (int kk = 0; kk < 32; kk++) a2 += hp[kk] * w2p[(size_t)kk * FOUT];
    part2[p][j] = a2;
  }
  __syncthreads();
  if (tid < FOUT) {
    float sv = part2[0][tid] + part2[1][tid] + part2[2][tid] + part2[3][tid] +
               part2[4][tid] + part2[5][tid] + part2[6][tid] + part2[7][tid];
    HW2[((size_t)k * MS2 + s) * FOUT + tid] = sv;
  }
}

// K6: mu rows + decoder MLP. All degree queries are slot nodes -> use bcnt.
__global__ __launch_bounds__(256) void k6_decode(const float* __restrict__ HW2,
                                                 const float* __restrict__ b2,
                                                 const int* __restrict__ cnt1,
                                                 const int* __restrict__ L1src,
                                                 const int* __restrict__ L1sel,
                                                 const int* __restrict__ idx,
                                                 const int* __restrict__ reg,
                                                 const int* __restrict__ bcnt,
                                                 const float* __restrict__ value,
                                                 const float* __restrict__ Wd,
                                                 const float* __restrict__ bd,
                                                 const float* __restrict__ Wp,
                                                 const float* __restrict__ bp,
                                                 float* __restrict__ out) {
  __shared__ float h[NH + 1];
  __shared__ float o[FHD];
  __shared__ float red[4];
  int k = blockIdx.x;
  int tid = threadIdx.x;
  const int* rk = reg + (size_t)k * NN;
  int n1 = min(cnt1[k], CAP1);
  int tsel = tid >> 7, j = tid & 127;
  int t = idx[2 * k + tsel];
  int tslot = rk[t] - 1;
  float dit = dinvf(bcnt[k * MS2 + tslot]);
  float acc = b2[j] + dit * dit * HW2[((size_t)k * MS2 + tslot) * FOUT + j];
  for (int i = 0; i < n1; i++) {
    if (L1sel[k * CAP1 + i] == tsel) {
      int s = L1src[k * CAP1 + i];
      int sslot = rk[s] - 1;
      float dis = dinvf(bcnt[k * MS2 + sslot]);
      acc += dis * dit * HW2[((size_t)k * MS2 + sslot) * FOUT + j];
    }
  }
  h[tsel * FOUT + j] = acc;
  if (tid < 3) h[2 * FOUT + tid] = value[k * 3 + tid];
  __syncthreads();
  float a2 = bd[tid];
  for (int i = 0; i < NH; i++) a2 += h[i] * Wd[(size_t)i * FHD + tid];
  o[tid] = a2 > 0.f ? a2 : 0.f;
  __syncthreads();
  float r = o[tid] * Wp[tid];
  for (int off2 = 32; off2 > 0; off2 >>= 1) r += __shfl_down(r, off2);
  if ((tid & 63) == 0) red[tid >> 6] = r;
  __syncthreads();
  if (tid == 0) {
    float ssum = red[0] + red[1] + red[2] + red[3] + bp[0];
    out[k] = 1.f / (1.f + expf(-ssum));
  }
}

extern "C" void kernel_launch(void* const* d_in, const int* in_sizes, int n_in,
                              void* d_out, int out_size, void* d_ws, size_t ws_size,
                              hipStream_t stream) {
  const float* x     = (const float*)d_in[0];
  const int*   ei    = (const int*)d_in[1];
  const float* value = (const float*)d_in[2];
  const int*   idx   = (const int*)d_in[3];
  const float* W1    = (const float*)d_in[4];
  const float* b1    = (const float*)d_in[5];
  const float* W2    = (const float*)d_in[6];
  const float* b2    = (const float*)d_in[7];
  const float* Wd    = (const float*)d_in[8];
  const float* bd    = (const float*)d_in[9];
  const float* Wp    = (const float*)d_in[10];
  const float* bp    = (const float*)d_in[11];
  float* out = (float*)d_out;

  char* ws = (char*)d_ws;
  size_t off = 0;
  auto alloc = [&](size_t bytes) -> void* {
    void* p = ws + off;
    off = (off + bytes + 255) & ~(size_t)255;
    return p;
  };
  // --- zeroed region (one kz_zero): reg, bcnt, cnt1, mslots ---
  int* reg   = (int*)alloc((size_t)(KK * NN + KK * MS2 + 2 * KK) * sizeof(int));
  int* bcnt  = reg + KK * NN;
  int* cnt1  = bcnt + KK * MS2;
  int* mslots = cnt1 + KK;
  size_t zbytes = (size_t)(KK * NN + KK * MS2 + 2 * KK) * sizeof(int);  // /16 exact
  // --- non-zeroed scratch ---
  int* L1src = (int*)alloc((size_t)KK * CAP1 * sizeof(int));
  int* L1sel = (int*)alloc((size_t)KK * CAP1 * sizeof(int));
  int* slotNode = (int*)alloc((size_t)KK * MS2 * sizeof(int));
  int* bucket = (int*)alloc((size_t)KK * MS2 * BCAP * sizeof(int));
  float* HW2 = (float*)alloc((size_t)KK * MS2 * FOUT * sizeof(float));
  unsigned* P = (unsigned*)alloc((size_t)KK * CH * NN * sizeof(unsigned));  // 5.1 MB, fully stored
  (void)ws_size; (void)in_sizes; (void)n_in; (void)out_size;

  int n4 = (int)(zbytes / 16);
  kz_zero<<<(n4 + 255) / 256, 256, 0, stream>>>((int4*)reg, n4);

  dim3 escan((E4 + 255) / 256, KK);
  k12_scan_claim<<<escan, 256, 0, stream>>>(ei, idx, cnt1, L1src, L1sel,
                                            reg, slotNode, mslots);
  k3h_scan<<<dim3(CH * 2, KK), 256, 0, stream>>>(ei, reg, bcnt, bucket, P);
  k5_slotmlp<<<dim3(MS2, KK), 1024, 0, stream>>>(slotNode, mslots, bcnt, bucket, P,
                                                 x, W1, b1, W2, HW2);
  k6_decode<<<dim3(KK), 256, 0, stream>>>(HW2, b2, cnt1, L1src, L1sel, idx, reg, bcnt,
                                          value, Wd, bd, Wp, bp, out);
}

// Round 14
// 81.789 us; speedup vs baseline: 1.5788x; 1.1099x over previous
//
#include <hip/hip_runtime.h>
#include <hip/hip_bf16.h>

// ROUND 14 diagnostic: round-8 pipeline (68.2µs known-good) + 3 shadow k12
// launches (same kernel, shadow output buffers). dur = 68.2 + 3*k12.

#define NN 20000
#define EE 320000
#define E4 (EE/4)
#define KK 4
#define FIN 512
#define FHID 256
#define FOUT 128
#define FHD 256
#define NH (2*FOUT+3)   // 259
#define CAP1 1024
#define MS2 128
#define BCAP 256

__device__ __forceinline__ float dinvf(int indeg) {
  // reference deg includes the self-loop -> always >= 1
  return rsqrtf((float)(indeg + 1));
}

__global__ __launch_bounds__(256) void kz_zero(int4* __restrict__ p, int n4) {
  int i = blockIdx.x * 256 + threadIdx.x;
  if (i < n4) p[i] = make_int4(0, 0, 0, 0);
}

// K12: scan dst planes; collect L1 edges AND inline CAS-claim slot nodes.
__global__ __launch_bounds__(256) void k12_scan_claim(const int* __restrict__ ei,
                                                      const int* __restrict__ idx,
                                                      int* __restrict__ cnt1,
                                                      int* __restrict__ L1src,
                                                      int* __restrict__ L1sel,
                                                      int* __restrict__ reg,
                                                      int* __restrict__ slotNode,
                                                      int* __restrict__ mslots) {
  int k = blockIdx.y;
  int* rk = reg + (size_t)k * NN;
  int t0 = idx[2 * k], t1 = idx[2 * k + 1];
  if (blockIdx.x == 0 && threadIdx.x < 2) {
    int node = (threadIdx.x == 0) ? t0 : t1;
    if (atomicCAS(&rk[node], 0, -2) == 0) {
      int s = atomicAdd(&mslots[k], 1);
      if (s < MS2) { slotNode[k * MS2 + s] = node; rk[node] = s + 1; }
    }
  }
  int e4 = blockIdx.x * blockDim.x + threadIdx.x;
  if (e4 >= E4) return;
  const int* srcp = ei + (size_t)k * 2 * EE;
  int4 d4 = ((const int4*)(srcp + EE))[e4];
  int ds[4] = {d4.x, d4.y, d4.z, d4.w};
  #pragma unroll
  for (int c = 0; c < 4; c++) {
    bool h0 = (ds[c] == t0), h1 = (ds[c] == t1);
    if (h0 || h1) {
      int u = srcp[e4 * 4 + c];
      if (h0) {
        int p = atomicAdd(&cnt1[k], 1);
        if (p < CAP1) { L1src[k * CAP1 + p] = u; L1sel[k * CAP1 + p] = 0; }
      }
      if (h1) {
        int p = atomicAdd(&cnt1[k], 1);
        if (p < CAP1) { L1src[k * CAP1 + p] = u; L1sel[k * CAP1 + p] = 1; }
      }
      if (atomicCAS(&rk[u], 0, -2) == 0) {
        int s = atomicAdd(&mslots[k], 1);
        if (s < MS2) { slotNode[k * MS2 + s] = u; rk[u] = s + 1; }
      }
    }
  }
}

// K3: scan; if dst is a slot node, append src to that slot's bucket; flag src
__global__ __launch_bounds__(256) void k3_scanL2(const int* __restrict__ ei,
                                                 int* __restrict__ reg,
                                                 int* __restrict__ bcnt,
                                                 int* __restrict__ bucket) {
  int k = blockIdx.y;
  int e4 = blockIdx.x * blockDim.x + threadIdx.x;
  if (e4 >= E4) return;
  const int* srcp = ei + (size_t)k * 2 * EE;
  int4 d4 = ((const int4*)(srcp + EE))[e4];
  int* rk = reg + (size_t)k * NN;
  int ds[4] = {d4.x, d4.y, d4.z, d4.w};
  #pragma unroll
  for (int c = 0; c < 4; c++) {
    int rv = rk[ds[c]];
    if (rv > 0) {
      int s = rv - 1;
      int u = srcp[e4 * 4 + c];
      int p = atomicAdd(&bcnt[k * MS2 + s], 1);
      if (p < BCAP) bucket[((size_t)k * MS2 + s) * BCAP + p] = u;
      if (rk[u] == 0) rk[u] = -1;  // benign race
    }
  }
}

// K4: scan; count in-degree only for flagged/registered nodes
__global__ __launch_bounds__(256) void k4_deg(const int* __restrict__ ei,
                                              const int* __restrict__ reg,
                                              int* __restrict__ deg) {
  int k = blockIdx.y;
  int e4 = blockIdx.x * blockDim.x + threadIdx.x;
  if (e4 >= E4) return;
  const int* dstp = ei + (size_t)k * 2 * EE + EE;
  int4 d4 = ((const int4*)dstp)[e4];
  const int* rk = reg + (size_t)k * NN;
  int ds[4] = {d4.x, d4.y, d4.z, d4.w};
  #pragma unroll
  for (int c = 0; c < 4; c++) {
    if (rk[ds[c]] != 0) atomicAdd(&deg[k * NN + ds[c]], 1);
  }
}

// K5: per slot (1024 thr): agg = dn*(dn*x[s] + sum du*x[u]); GEMV1+relu+GEMV2
__global__ __launch_bounds__(1024) void k5_slotmlp(const int* __restrict__ slotNode,
                                                   const int* __restrict__ mslots,
                                                   const int* __restrict__ bcnt,
                                                   const int* __restrict__ bucket,
                                                   const int* __restrict__ deg,
                                                   const float* __restrict__ x,
                                                   const float* __restrict__ W1,
                                                   const float* __restrict__ b1,
                                                   const float* __restrict__ W2,
                                                   float* __restrict__ HW2) {
  __shared__ float aggS[FIN];
  __shared__ float gtmp[FIN];
  __shared__ float part[4][FHID];
  __shared__ float hrow[FHID];
  __shared__ float part2[8][FOUT];
  __shared__ int   uS[BCAP];
  __shared__ float duS[BCAP];
  int k = blockIdx.y, s = blockIdx.x;
  if (s >= mslots[k]) return;
  int tid = threadIdx.x;
  int node = slotNode[k * MS2 + s];
  int nb = min(bcnt[k * MS2 + s], BCAP);
  const int* bk = bucket + ((size_t)k * MS2 + s) * BCAP;
  for (int e = tid; e < nb; e += 1024) {
    int u = bk[e];
    uS[e] = u;
    duS[e] = dinvf(deg[k * NN + u]);
  }
  __syncthreads();
  float dn = dinvf(deg[k * NN + node]);
  int f = tid & (FIN - 1), half = tid >> 9;
  float a = (half == 0) ? dn * x[(size_t)node * FIN + f] : 0.f;
  for (int e = half; e < nb; e += 2) a += duS[e] * x[(size_t)uS[e] * FIN + f];
  if (half == 1) gtmp[f] = a;
  __syncthreads();
  if (half == 0) aggS[f] = dn * (a + gtmp[f]);
  __syncthreads();
  {
    int q = tid >> 8, j = tid & (FHID - 1);
    float acc = 0.f;
    const float* w1p = W1 + (size_t)(q * 128) * FHID + j;
    const float* ap = aggS + q * 128;
    #pragma unroll 8
    for (int kk = 0; kk < 128; kk++) acc += ap[kk] * w1p[(size_t)kk * FHID];
    part[q][j] = acc;
  }
  __syncthreads();
  if (tid < FHID) {
    float v = part[0][tid] + part[1][tid] + part[2][tid] + part[3][tid] + b1[tid];
    hrow[tid] = v > 0.f ? v : 0.f;
  }
  __syncthreads();
  {
    int p = tid >> 7, j = tid & (FOUT - 1);
    float a2 = 0.f;
    const float* w2p = W2 + (size_t)(p * 32) * FOUT + j;
    const float* hp = hrow + p * 32;
    #pragma unroll 8
    for (int kk = 0; kk < 32; kk++) a2 += hp[kk] * w2p[(size_t)kk * FOUT];
    part2[p][j] = a2;
  }
  __syncthreads();
  if (tid < FOUT) {
    float sv = part2[0][tid] + part2[1][tid] + part2[2][tid] + part2[3][tid] +
               part2[4][tid] + part2[5][tid] + part2[6][tid] + part2[7][tid];
    HW2[((size_t)k * MS2 + s) * FOUT + tid] = sv;
  }
}

// K6: mu rows + decoder MLP -> sigmoid -> out[k]
__global__ __launch_bounds__(256) void k6_decode(const float* __restrict__ HW2,
                                                 const float* __restrict__ b2,
                                                 const int* __restrict__ cnt1,
                                                 const int* __restrict__ L1src,
                                                 const int* __restrict__ L1sel,
                                                 const int* __restrict__ idx,
                                                 const int* __restrict__ reg,
                                                 const int* __restrict__ deg,
                                                 const float* __restrict__ value,
                                                 const float* __restrict__ Wd,
                                                 const float* __restrict__ bd,
                                                 const float* __restrict__ Wp,
                                                 const float* __restrict__ bp,
                                                 float* __restrict__ out) {
  __shared__ float h[NH + 1];
  __shared__ float o[FHD];
  __shared__ float red[4];
  int k = blockIdx.x;
  int tid = threadIdx.x;
  const int* rk = reg + (size_t)k * NN;
  int n1 = min(cnt1[k], CAP1);
  int tsel = tid >> 7, j = tid & 127;
  int t = idx[2 * k + tsel];
  float dit = dinvf(deg[k * NN + t]);
  int tslot = rk[t] - 1;
  float acc = b2[j] + dit * dit * HW2[((size_t)k * MS2 + tslot) * FOUT + j];
  for (int i = 0; i < n1; i++) {
    if (L1sel[k * CAP1 + i] == tsel) {
      int s = L1src[k * CAP1 + i];
      float dis = dinvf(deg[k * NN + s]);
      int sslot = rk[s] - 1;
      acc += dis * dit * HW2[((size_t)k * MS2 + sslot) * FOUT + j];
    }
  }
  h[tsel * FOUT + j] = acc;
  if (tid < 3) h[2 * FOUT + tid] = value[k * 3 + tid];
  __syncthreads();
  float a2 = bd[tid];
  for (int i = 0; i < NH; i++) a2 += h[i] * Wd[(size_t)i * FHD + tid];
  o[tid] = a2 > 0.f ? a2 : 0.f;
  __syncthreads();
  float r = o[tid] * Wp[tid];
  for (int off2 = 32; off2 > 0; off2 >>= 1) r += __shfl_down(r, off2);
  if ((tid & 63) == 0) red[tid >> 6] = r;
  __syncthreads();
  if (tid == 0) {
    float ssum = red[0] + red[1] + red[2] + red[3] + bp[0];
    out[k] = 1.f / (1.f + expf(-ssum));
  }
}

extern "C" void kernel_launch(void* const* d_in, const int* in_sizes, int n_in,
                              void* d_out, int out_size, void* d_ws, size_t ws_size,
                              hipStream_t stream) {
  const float* x     = (const float*)d_in[0];
  const int*   ei    = (const int*)d_in[1];
  const float* value = (const float*)d_in[2];
  const int*   idx   = (const int*)d_in[3];
  const float* W1    = (const float*)d_in[4];
  const float* b1    = (const float*)d_in[5];
  const float* W2    = (const float*)d_in[6];
  const float* b2    = (const float*)d_in[7];
  const float* Wd    = (const float*)d_in[8];
  const float* bd    = (const float*)d_in[9];
  const float* Wp    = (const float*)d_in[10];
  const float* bp    = (const float*)d_in[11];
  float* out = (float*)d_out;

  char* ws = (char*)d_ws;
  size_t off = 0;
  auto alloc = [&](size_t bytes) -> void* {
    void* p = ws + off;
    off = (off + bytes + 255) & ~(size_t)255;
    return p;
  };
  // --- zeroed region (one kz_zero): reg, deg, bcnt, cnt1, mslots, regB, cnt1B, mslotsB ---
  size_t zints = (size_t)(2 * KK * NN + KK * MS2 + 2 * KK)    // real
               + (size_t)(KK * NN + 2 * KK);                  // shadow
  int* reg    = (int*)alloc(zints * sizeof(int));
  int* deg    = reg + KK * NN;
  int* bcnt   = deg + KK * NN;
  int* cnt1   = bcnt + KK * MS2;
  int* mslots = cnt1 + KK;
  int* regB    = mslots + KK;
  int* cnt1B   = regB + KK * NN;
  int* mslotsB = cnt1B + KK;
  size_t zbytes = zints * sizeof(int);   // 962,112 B -> /16 exact
  // --- non-zeroed scratch ---
  int* L1src = (int*)alloc((size_t)KK * CAP1 * sizeof(int));
  int* L1sel = (int*)alloc((size_t)KK * CAP1 * sizeof(int));
  int* slotNode = (int*)alloc((size_t)KK * MS2 * sizeof(int));
  int* bucket = (int*)alloc((size_t)KK * MS2 * BCAP * sizeof(int));
  float* HW2 = (float*)alloc((size_t)KK * MS2 * FOUT * sizeof(float));
  int* L1srcB = (int*)alloc((size_t)KK * CAP1 * sizeof(int));
  int* L1selB = (int*)alloc((size_t)KK * CAP1 * sizeof(int));
  int* slotNodeB = (int*)alloc((size_t)KK * MS2 * sizeof(int));
  (void)ws_size; (void)in_sizes; (void)n_in; (void)out_size;

  int n4 = (int)(zbytes / 16);
  dim3 escan((E4 + 255) / 256, KK);

  kz_zero<<<(n4 + 255) / 256, 256, 0, stream>>>((int4*)reg, n4);
  k12_scan_claim<<<escan, 256, 0, stream>>>(ei, idx, cnt1, L1src, L1sel,
                                            reg, slotNode, mslots);
  k3_scanL2<<<escan, 256, 0, stream>>>(ei, reg, bcnt, bucket);
  k4_deg<<<escan, 256, 0, stream>>>(ei, reg, deg);
  k5_slotmlp<<<dim3(MS2, KK), 1024, 0, stream>>>(slotNode, mslots, bcnt, bucket, deg,
                                                 x, W1, b1, W2, HW2);
  k6_decode<<<dim3(KK), 256, 0, stream>>>(HW2, b2, cnt1, L1src, L1sel, idx, reg, deg,
                                          value, Wd, bd, Wp, bp, out);

  // --- diagnostic amplification: 3 shadow k12 runs (outputs never read;
  //     shadow counters re-zeroed by kz at the start of every replay) ---
  for (int rep = 0; rep < 3; rep++) {
    k12_scan_claim<<<escan, 256, 0, stream>>>(ei, idx, cnt1B, L1srcB, L1selB,
                                              regB, slotNodeB, mslotsB);
  }
}

// Round 15
// 59.654 us; speedup vs baseline: 2.1645x; 1.3710x over previous
//
#include <hip/hip_runtime.h>
#include <hip/hip_bf16.h>

#define NN 20000
#define EE 320000
#define E4 (EE/4)
#define KK 4
#define FIN 512
#define FHID 256
#define FOUT 128
#define FHD 256
#define NH (2*FOUT+3)   // 259
#define CAP1 1024
#define MS2 128
#define BCAP 256
#define BMW 640         // bitmap words per plane (20000 bits -> 625, padded)

__device__ __forceinline__ float dinvf(int indeg) {
  // reference deg includes the self-loop -> always >= 1
  return rsqrtf((float)(indeg + 1));
}

__global__ __launch_bounds__(256) void kz_zero(int4* __restrict__ p, int n4) {
  int i = blockIdx.x * 256 + threadIdx.x;
  if (i < n4) p[i] = make_int4(0, 0, 0, 0);
}

// K12: scan dst planes; collect L1 edges, CAS-claim slot nodes, set slot bitmap.
__global__ __launch_bounds__(256) void k12_scan_claim(const int* __restrict__ ei,
                                                      const int* __restrict__ idx,
                                                      int* __restrict__ cnt1,
                                                      int* __restrict__ L1src,
                                                      int* __restrict__ L1sel,
                                                      int* __restrict__ reg,
                                                      int* __restrict__ slotNode,
                                                      int* __restrict__ mslots,
                                                      unsigned* __restrict__ bA) {
  int k = blockIdx.y;
  int* rk = reg + (size_t)k * NN;
  unsigned* bAk = bA + k * BMW;
  int t0 = idx[2 * k], t1 = idx[2 * k + 1];
  if (blockIdx.x == 0 && threadIdx.x < 2) {
    int node = (threadIdx.x == 0) ? t0 : t1;
    if (atomicCAS(&rk[node], 0, -2) == 0) {
      int s = atomicAdd(&mslots[k], 1);
      if (s < MS2) {
        slotNode[k * MS2 + s] = node; rk[node] = s + 1;
        atomicOr(&bAk[node >> 5], 1u << (node & 31));
      }
    }
  }
  int e4 = blockIdx.x * blockDim.x + threadIdx.x;
  if (e4 >= E4) return;
  const int* srcp = ei + (size_t)k * 2 * EE;
  int4 d4 = ((const int4*)(srcp + EE))[e4];
  int ds[4] = {d4.x, d4.y, d4.z, d4.w};
  #pragma unroll
  for (int c = 0; c < 4; c++) {
    bool h0 = (ds[c] == t0), h1 = (ds[c] == t1);
    if (h0 || h1) {
      int u = srcp[e4 * 4 + c];
      if (h0) {
        int p = atomicAdd(&cnt1[k], 1);
        if (p < CAP1) { L1src[k * CAP1 + p] = u; L1sel[k * CAP1 + p] = 0; }
      }
      if (h1) {
        int p = atomicAdd(&cnt1[k], 1);
        if (p < CAP1) { L1src[k * CAP1 + p] = u; L1sel[k * CAP1 + p] = 1; }
      }
      if (atomicCAS(&rk[u], 0, -2) == 0) {
        int s = atomicAdd(&mslots[k], 1);
        if (s < MS2) {
          slotNode[k * MS2 + s] = u; rk[u] = s + 1;
          atomicOr(&bAk[u >> 5], 1u << (u & 31));
        }
      }
    }
  }
}

// K3: scan with LDS slot-bitmap membership test (no per-edge global table reads).
// On hit: slot id via rk[], bucket append, mark source in deg-needed bitmap bB.
__global__ __launch_bounds__(256) void k3_scanL2(const int* __restrict__ ei,
                                                 const int* __restrict__ reg,
                                                 const unsigned* __restrict__ bA,
                                                 unsigned* __restrict__ bB,
                                                 int* __restrict__ bcnt,
                                                 int* __restrict__ bucket) {
  __shared__ unsigned lbA[BMW];   // 2.5 KB
  int k = blockIdx.y;
  const unsigned* bAk = bA + k * BMW;
  for (int i = threadIdx.x; i < BMW; i += 256) lbA[i] = bAk[i];
  __syncthreads();
  int e4 = blockIdx.x * blockDim.x + threadIdx.x;
  if (e4 >= E4) return;
  const int* srcp = ei + (size_t)k * 2 * EE;
  int4 d4 = ((const int4*)(srcp + EE))[e4];
  const int* rk = reg + (size_t)k * NN;
  unsigned* bBk = bB + k * BMW;
  int ds[4] = {d4.x, d4.y, d4.z, d4.w};
  #pragma unroll
  for (int c = 0; c < 4; c++) {
    int d = ds[c];
    if ((lbA[d >> 5] >> (d & 31)) & 1u) {
      int s = rk[d] - 1;
      int u = srcp[e4 * 4 + c];
      int p = atomicAdd(&bcnt[k * MS2 + s], 1);
      if (p < BCAP) bucket[((size_t)k * MS2 + s) * BCAP + p] = u;
      atomicOr(&bBk[u >> 5], 1u << (u & 31));
    }
  }
}

// K4: scan with LDS deg-needed-bitmap test; sparse atomicAdd for hits only.
__global__ __launch_bounds__(256) void k4_deg(const int* __restrict__ ei,
                                              const unsigned* __restrict__ bB,
                                              int* __restrict__ deg) {
  __shared__ unsigned lbB[BMW];
  int k = blockIdx.y;
  const unsigned* bBk = bB + k * BMW;
  for (int i = threadIdx.x; i < BMW; i += 256) lbB[i] = bBk[i];
  __syncthreads();
  int e4 = blockIdx.x * blockDim.x + threadIdx.x;
  if (e4 >= E4) return;
  const int4* dst4 = (const int4*)(ei + (size_t)k * 2 * EE + EE);
  int4 d4 = dst4[e4];
  int ds[4] = {d4.x, d4.y, d4.z, d4.w};
  #pragma unroll
  for (int c = 0; c < 4; c++) {
    int d = ds[c];
    if ((lbB[d >> 5] >> (d & 31)) & 1u) atomicAdd(&deg[k * NN + d], 1);
  }
}

// K5: per slot (1024 thr). Slot degree = raw bcnt. Gather 8-way group-parallel
// with float4 rows (8 rows in flight); LDS reduce; GEMV1+relu+GEMV2.
__global__ __launch_bounds__(1024) void k5_slotmlp(const int* __restrict__ slotNode,
                                                   const int* __restrict__ mslots,
                                                   const int* __restrict__ bcnt,
                                                   const int* __restrict__ bucket,
                                                   const int* __restrict__ deg,
                                                   const float* __restrict__ x,
                                                   const float* __restrict__ W1,
                                                   const float* __restrict__ b1,
                                                   const float* __restrict__ W2,
                                                   float* __restrict__ HW2) {
  __shared__ float partg[8][FIN];   // 16 KB gather partials
  __shared__ float aggS[FIN];       // 2 KB
  __shared__ float part[4][FHID];   // 4 KB
  __shared__ float hrow[FHID];      // 1 KB
  __shared__ float part2[8][FOUT];  // 4 KB
  __shared__ int   uS[BCAP];        // 1 KB
  __shared__ float duS[BCAP];       // 1 KB
  int k = blockIdx.y, s = blockIdx.x;
  if (s >= mslots[k]) return;
  int tid = threadIdx.x;
  int node = slotNode[k * MS2 + s];
  int rawbc = bcnt[k * MS2 + s];
  int nb = min(rawbc, BCAP);
  const int* bk = bucket + ((size_t)k * MS2 + s) * BCAP;
  if (tid < nb) {
    int u = bk[tid];
    uS[tid] = u;
    duS[tid] = dinvf(deg[k * NN + u]);
  }
  __syncthreads();
  float dn = dinvf(rawbc);   // raw bcnt == slot in-degree (validated r13)
  int g = tid >> 7, f4 = tid & 127;
  float ax = 0.f, ay = 0.f, az = 0.f, aw = 0.f;
  if (g == 0) {   // self-loop row, weight dn
    float4 v = ((const float4*)(x + (size_t)node * FIN))[f4];
    ax = dn * v.x; ay = dn * v.y; az = dn * v.z; aw = dn * v.w;
  }
  for (int e = g; e < nb; e += 8) {
    float du = duS[e];
    float4 v = ((const float4*)(x + (size_t)uS[e] * FIN))[f4];
    ax += du * v.x; ay += du * v.y; az += du * v.z; aw += du * v.w;
  }
  { float* pw = &partg[g][f4 * 4]; pw[0] = ax; pw[1] = ay; pw[2] = az; pw[3] = aw; }
  __syncthreads();
  if (tid < FIN) {
    float ssum = 0.f;
    #pragma unroll
    for (int g2 = 0; g2 < 8; g2++) ssum += partg[g2][tid];
    aggS[tid] = dn * ssum;
  }
  __syncthreads();
  {
    int q = tid >> 8, j = tid & (FHID - 1);
    float acc = 0.f;
    const float* w1p = W1 + (size_t)(q * 128) * FHID + j;
    const float* ap = aggS + q * 128;
    #pragma unroll 8
    for (int kk = 0; kk < 128; kk++) acc += ap[kk] * w1p[(size_t)kk * FHID];
    part[q][j] = acc;
  }
  __syncthreads();
  if (tid < FHID) {
    float v = part[0][tid] + part[1][tid] + part[2][tid] + part[3][tid] + b1[tid];
    hrow[tid] = v > 0.f ? v : 0.f;
  }
  __syncthreads();
  {
    int p = tid >> 7, j = tid & (FOUT - 1);
    float a2 = 0.f;
    const float* w2p = W2 + (size_t)(p * 32) * FOUT + j;
    const float* hp = hrow + p * 32;
    #pragma unroll 8
    for (int kk = 0; kk < 32; kk++) a2 += hp[kk] * w2p[(size_t)kk * FOUT];
    part2[p][j] = a2;
  }
  __syncthreads();
  if (tid < FOUT) {
    float sv = part2[0][tid] + part2[1][tid] + part2[2][tid] + part2[3][tid] +
               part2[4][tid] + part2[5][tid] + part2[6][tid] + part2[7][tid];
    HW2[((size_t)k * MS2 + s) * FOUT + tid] = sv;
  }
}

// K6: mu rows + decoder. All degree queries are slot nodes -> bcnt (r13-validated).
__global__ __launch_bounds__(256) void k6_decode(const float* __restrict__ HW2,
                                                 const float* __restrict__ b2,
                                                 const int* __restrict__ cnt1,
                                                 const int* __restrict__ L1src,
                                                 const int* __restrict__ L1sel,
                                                 const int* __restrict__ idx,
                                                 const int* __restrict__ reg,
                                                 const int* __restrict__ bcnt,
                                                 const float* __restrict__ value,
                                                 const float* __restrict__ Wd,
                                                 const float* __restrict__ bd,
                                                 const float* __restrict__ Wp,
                                                 const float* __restrict__ bp,
                                                 float* __restrict__ out) {
  __shared__ float h[NH + 1];
  __shared__ float o[FHD];
  __shared__ float red[4];
  int k = blockIdx.x;
  int tid = threadIdx.x;
  const int* rk = reg + (size_t)k * NN;
  int n1 = min(cnt1[k], CAP1);
  int tsel = tid >> 7, j = tid & 127;
  int t = idx[2 * k + tsel];
  int tslot = rk[t] - 1;
  float dit = dinvf(bcnt[k * MS2 + tslot]);
  float acc = b2[j] + dit * dit * HW2[((size_t)k * MS2 + tslot) * FOUT + j];
  for (int i = 0; i < n1; i++) {
    if (L1sel[k * CAP1 + i] == tsel) {
      int s = L1src[k * CAP1 + i];
      int sslot = rk[s] - 1;
      float dis = dinvf(bcnt[k * MS2 + sslot]);
      acc += dis * dit * HW2[((size_t)k * MS2 + sslot) * FOUT + j];
    }
  }
  h[tsel * FOUT + j] = acc;
  if (tid < 3) h[2 * FOUT + tid] = value[k * 3 + tid];
  __syncthreads();
  float a2 = bd[tid];
  for (int i = 0; i < NH; i++) a2 += h[i] * Wd[(size_t)i * FHD + tid];
  o[tid] = a2 > 0.f ? a2 : 0.f;
  __syncthreads();
  float r = o[tid] * Wp[tid];
  for (int off2 = 32; off2 > 0; off2 >>= 1) r += __shfl_down(r, off2);
  if ((tid & 63) == 0) red[tid >> 6] = r;
  __syncthreads();
  if (tid == 0) {
    float ssum = red[0] + red[1] + red[2] + red[3] + bp[0];
    out[k] = 1.f / (1.f + expf(-ssum));
  }
}

extern "C" void kernel_launch(void* const* d_in, const int* in_sizes, int n_in,
                              void* d_out, int out_size, void* d_ws, size_t ws_size,
                              hipStream_t stream) {
  const float* x     = (const float*)d_in[0];
  const int*   ei    = (const int*)d_in[1];
  const float* value = (const float*)d_in[2];
  const int*   idx   = (const int*)d_in[3];
  const float* W1    = (const float*)d_in[4];
  const float* b1    = (const float*)d_in[5];
  const float* W2    = (const float*)d_in[6];
  const float* b2    = (const float*)d_in[7];
  const float* Wd    = (const float*)d_in[8];
  const float* bd    = (const float*)d_in[9];
  const float* Wp    = (const float*)d_in[10];
  const float* bp    = (const float*)d_in[11];
  float* out = (float*)d_out;

  char* ws = (char*)d_ws;
  size_t off = 0;
  auto alloc = [&](size_t bytes) -> void* {
    void* p = ws + off;
    off = (off + bytes + 255) & ~(size_t)255;
    return p;
  };
  // --- zeroed region (one kz_zero): reg, deg, bA, bB, bcnt, cnt1, mslots ---
  size_t zints = (size_t)(2 * KK * NN + 2 * KK * BMW + KK * MS2 + 2 * KK);
  int* reg   = (int*)alloc(zints * sizeof(int));
  int* deg   = reg + KK * NN;
  unsigned* bA = (unsigned*)(deg + KK * NN);
  unsigned* bB = bA + KK * BMW;
  int* bcnt  = (int*)(bB + KK * BMW);
  int* cnt1  = bcnt + KK * MS2;
  int* mslots = cnt1 + KK;
  size_t zbytes = zints * sizeof(int);   // 662,560 B -> /16 exact
  // --- non-zeroed scratch ---
  int* L1src = (int*)alloc((size_t)KK * CAP1 * sizeof(int));
  int* L1sel = (int*)alloc((size_t)KK * CAP1 * sizeof(int));
  int* slotNode = (int*)alloc((size_t)KK * MS2 * sizeof(int));
  int* bucket = (int*)alloc((size_t)KK * MS2 * BCAP * sizeof(int));
  float* HW2 = (float*)alloc((size_t)KK * MS2 * FOUT * sizeof(float));
  (void)ws_size; (void)in_sizes; (void)n_in; (void)out_size;

  int n4 = (int)(zbytes / 16);
  dim3 escan((E4 + 255) / 256, KK);

  kz_zero<<<(n4 + 255) / 256, 256, 0, stream>>>((int4*)reg, n4);
  k12_scan_claim<<<escan, 256, 0, stream>>>(ei, idx, cnt1, L1src, L1sel,
                                            reg, slotNode, mslots, bA);
  k3_scanL2<<<escan, 256, 0, stream>>>(ei, reg, bA, bB, bcnt, bucket);
  k4_deg<<<escan, 256, 0, stream>>>(ei, bB, deg);
  k5_slotmlp<<<dim3(MS2, KK), 1024, 0, stream>>>(slotNode, mslots, bcnt, bucket, deg,
                                                 x, W1, b1, W2, HW2);
  k6_decode<<<dim3(KK), 256, 0, stream>>>(HW2, b2, cnt1, L1src, L1sel, idx, reg, bcnt,
                                          value, Wd, bd, Wp, bp, out);
}